// Round 14
// baseline (285.561 us; speedup 1.0000x reference)
//
#include <hip/hip_runtime.h>

// GCN forward. All inter-kernel feature traffic in bf16.
//   xb  = bf16(x * dinv_row)                       (fused into scatter)
//   axb = bf16(dd*(Σ_{s} xb[s] + xb[d]))           (agg1, bf16 out)
//   a1  = relu(axb@W1 + b1)                        (MFMA GEMM, bf16 out)
//   h2b = bf16((a1@W2) * dinv_row)                 (MFMA GEMM, bf16 out)
//   a2b = bf16(relu(dd*(Σ h2b[s] + h2b[d]) + b2))  (agg2, bf16 out)
//   out = meanpool(a2b)@Wfc + bfc
// R14 vs r13: agg processes the feature dim in TWO half-planes (64 dims each).
// Waves on one half touch a 6.4MB slice of the gather table -> fits per-XCD L2
// (12.8MB didn't; agg was L2-miss-path bound at ~1.2-2.3 TB/s). One dispatch;
// first half of blocks (dispatch-order monotonic) = plane 0. 1 line/edge gather.

constexpr int IN_DIM  = 128;
constexpr int HID     = 256;
constexpr int HID2    = 128;
constexpr int OUT_DIM = 4;
constexpr int NGRAPH  = 64;
constexpr int PCH     = 64;   // nodes per pool block
constexpr int TP      = 132;  // epilogue LDS tile pitch (shorts)

typedef __attribute__((ext_vector_type(8))) short bf16x8;
typedef __attribute__((ext_vector_type(4))) float f32x4;

__device__ __forceinline__ short f2bf(float f) {
    union { float f; unsigned u; } v; v.f = f;
    unsigned r = v.u + 0x7fff + ((v.u >> 16) & 1);   // RNE
    return (short)(r >> 16);
}
__device__ __forceinline__ float bf2f(short s) {
    union { unsigned u; float f; } v; v.u = ((unsigned)(unsigned short)s) << 16;
    return v.f;
}

// ---------------- W prep (both layers) + count zero ----------------

__global__ void wprep_all_kernel(const float* __restrict__ W1, short* __restrict__ W1th,
                                 short* __restrict__ W1tl,
                                 const float* __restrict__ W2, short* __restrict__ W2th,
                                 short* __restrict__ W2tl,
                                 int* __restrict__ count, int N) {
    int i = blockIdx.x * blockDim.x + threadIdx.x;
    if (i < IN_DIM * HID) {
        int k = i / HID, n = i % HID;
        float w = W1[i];
        short h = f2bf(w);
        W1th[n * IN_DIM + k] = h;
        W1tl[n * IN_DIM + k] = f2bf(w - bf2f(h));
    }
    if (i < HID * HID2) {
        int k = i / HID2, n = i % HID2;
        float w = W2[i];
        short h = f2bf(w);
        W2th[n * HID + k] = h;
        W2tl[n * HID + k] = f2bf(w - bf2f(h));
    }
    if (i < N) count[i] = 0;
}

// ---------------- CSR build ----------------
// hist: count in-degree AND record each edge's rank within its dst row.

__global__ void hist_kernel(const int* __restrict__ dst, int* __restrict__ count,
                            ushort* __restrict__ rank, int E) {
    int i = blockIdx.x * blockDim.x + threadIdx.x;
    if (i < E) rank[i] = (ushort)atomicAdd(&count[dst[i]], 1);
}

__global__ void scan1_kernel(const int* __restrict__ count, int* __restrict__ bsums, int N) {
    __shared__ int s[256];
    int t = threadIdx.x, i = blockIdx.x * 256 + t;
    int v = (i < N) ? count[i] : 0;
    s[t] = v; __syncthreads();
    for (int o = 1; o < 256; o <<= 1) {
        int x = (t >= o) ? s[t - o] : 0;
        __syncthreads(); s[t] += x; __syncthreads();
    }
    if (t == 255) bsums[blockIdx.x] = s[255];
}

// exclusive scan of block sums (nb <= 256) + pool zeroing (piggyback)
__global__ void scan2_kernel(int* __restrict__ bsums, int nb, float* __restrict__ pool) {
    __shared__ int s[256];
    int t = threadIdx.x;
    int v = (t < nb) ? bsums[t] : 0;
    s[t] = v; __syncthreads();
    for (int o = 1; o < 256; o <<= 1) {
        int x = (t >= o) ? s[t - o] : 0;
        __syncthreads(); s[t] += x; __syncthreads();
    }
    if (t < nb) bsums[t] = s[t] - v;
    for (int i = t; i < NGRAPH * HID2; i += 256) pool[i] = 0.f;
}

__global__ void scan3_kernel(const int* __restrict__ count, const int* __restrict__ bsums,
                             int* __restrict__ rowptr, float* __restrict__ dinv, int N, int E) {
    __shared__ int s[256];
    int t = threadIdx.x, i = blockIdx.x * 256 + t;
    int v = (i < N) ? count[i] : 0;
    s[t] = v; __syncthreads();
    for (int o = 1; o < 256; o <<= 1) {
        int x = (t >= o) ? s[t - o] : 0;
        __syncthreads(); s[t] += x; __syncthreads();
    }
    if (i < N) {
        int ex = bsums[blockIdx.x] + s[t] - v;
        rowptr[i] = ex;
        dinv[i] = rsqrtf((float)v + 1.0f);
        if (i == 0) rowptr[N] = E;
    }
}

// scatter (no atomics: p = rowptr[dst]+rank) + xb = bf16(x * dinv_row)
__global__ void scatter_scale_kernel(const int* __restrict__ src, const int* __restrict__ dst,
                                     const ushort* __restrict__ rank,
                                     const int* __restrict__ rowptr, ushort* __restrict__ csr,
                                     const float* __restrict__ x, const float* __restrict__ dinv,
                                     ushort* __restrict__ xb, int E, int total2) {
    int i = blockIdx.x * blockDim.x + threadIdx.x;
    if (i < E) {
        int p = rowptr[dst[i]] + (int)rank[i];
        csr[p] = (ushort)src[i];
    }
    if (i < total2) {
        float d = dinv[i >> 6];
        float2 v = ((const float2*)x)[i];
        ushort2 o;
        o.x = (ushort)f2bf(v.x * d);
        o.y = (ushort)f2bf(v.y * d);
        ((ushort2*)xb)[i] = o;
    }
}

// ---------------- split-bf16 LDS-tiled MFMA GEMM, bf16 output ----------------
// Cb[M,N] = post( (Ah[+Al]) @ (Bh+Bl)^T ), B given N x K (transposed).
// Block: 128x128 tile, 256 thr. ALO: A has a lo plane (3 MFMAs) else 2 MFMAs.
// LDS slab = 16x32 tile in MFMA fragment order; single ds_read_b128 per frag.
// C/D layout (16x16x32): col=lane&15, row=(lane>>4)*4+reg [verified m89/m91].
// Epilogue: acc -> padded LDS bf16 tile (pitch TP=132) -> coalesced 16B stores.
// RELU: v=relu(v+bias[col]).  SCALED: v*=dinv[row] (pre-scale for gather table).

template <int K, int N, bool ALO, bool RELU, bool SCALED>
__launch_bounds__(256)
__global__ void gemm_tile_kernel(const short* __restrict__ Ah, const short* __restrict__ Al,
                                 const short* __restrict__ Bh, const short* __restrict__ Bl,
                                 const float* __restrict__ bias,
                                 const float* __restrict__ dinv,
                                 short* __restrict__ Cb, int M) {
    __shared__ __align__(16) short LDSBUF[128 * TP];     // 33792 B >= 32 KB staging
    short (*S)[8][512] = (short (*)[8][512])LDSBUF;      // staging view [4][8][512]

    const int tid  = threadIdx.x;
    const int wave = tid >> 6;
    const int lane = tid & 63;
    const int row0 = blockIdx.y * 128;
    const int col0 = blockIdx.x * 128;

    const int l15 = lane & 15;
    const int kq  = (lane >> 4) * 8;

    f32x4 acc[4][4];
#pragma unroll
    for (int i = 0; i < 4; ++i)
#pragma unroll
        for (int j = 0; j < 4; ++j) acc[i][j] = f32x4{0.f, 0.f, 0.f, 0.f};

    const int mt0 = (wave & 1) * 4;
    const int nt0 = (wave >> 1) * 4;

    for (int kb = 0; kb < K; kb += 32) {
        // ---- staging: constant-bound loops only ----
        if (ALO) {
            const short* gsrc = (wave == 0) ? Ah : (wave == 1) ? Al : (wave == 2) ? Bh : Bl;
            const bool isA = wave < 2;
            const int rb = (isA ? row0 : col0) + l15;
            bf16x8 stg[8];
#pragma unroll
            for (int j = 0; j < 8; ++j) {
                int rr = rb + j * 16;
                if (isA && rr >= M) rr = M - 1;       // clamp tail rows (stores guarded)
                stg[j] = *(const bf16x8*)(gsrc + (size_t)rr * K + kb + kq);
            }
#pragma unroll
            for (int j = 0; j < 8; ++j)
                *(bf16x8*)&S[wave][j][lane * 8] = stg[j];
        } else {
            if (wave < 2) {
                const int rb = row0 + l15;
                bf16x8 stg[4];
#pragma unroll
                for (int j = 0; j < 4; ++j) {
                    int rr = rb + (wave * 4 + j) * 16;
                    if (rr >= M) rr = M - 1;
                    stg[j] = *(const bf16x8*)(Ah + (size_t)rr * K + kb + kq);
                }
#pragma unroll
                for (int j = 0; j < 4; ++j)
                    *(bf16x8*)&S[0][wave * 4 + j][lane * 8] = stg[j];
            } else {
                const short* gsrc = (wave == 2) ? Bh : Bl;
                const int rb = col0 + l15;
                bf16x8 stg[8];
#pragma unroll
                for (int j = 0; j < 8; ++j)
                    stg[j] = *(const bf16x8*)(gsrc + (size_t)(rb + j * 16) * K + kb + kq);
#pragma unroll
                for (int j = 0; j < 8; ++j)
                    *(bf16x8*)&S[wave][j][lane * 8] = stg[j];
            }
        }
        __syncthreads();

        bf16x8 ah[4], al[4], bh[4], bl[4];
#pragma unroll
        for (int i = 0; i < 4; ++i) {
            ah[i] = *(const bf16x8*)&S[0][mt0 + i][lane * 8];
            if (ALO) al[i] = *(const bf16x8*)&S[1][mt0 + i][lane * 8];
            bh[i] = *(const bf16x8*)&S[2][nt0 + i][lane * 8];
            bl[i] = *(const bf16x8*)&S[3][nt0 + i][lane * 8];
        }
#pragma unroll
        for (int i = 0; i < 4; ++i)
#pragma unroll
            for (int j = 0; j < 4; ++j) {
                acc[i][j] = __builtin_amdgcn_mfma_f32_16x16x32_bf16(ah[i], bh[j], acc[i][j], 0, 0, 0);
                acc[i][j] = __builtin_amdgcn_mfma_f32_16x16x32_bf16(ah[i], bl[j], acc[i][j], 0, 0, 0);
                if (ALO)
                    acc[i][j] = __builtin_amdgcn_mfma_f32_16x16x32_bf16(al[i], bh[j], acc[i][j], 0, 0, 0);
            }
        __syncthreads();
    }

    // ---- epilogue: acc -> padded LDS bf16 tile -> coalesced stores ----
    short* T = LDSBUF;                      // 128 x TP shorts
    const int lrow_b = (wave & 1) * 64 + (lane >> 4) * 4;
    const int lcol_b = (wave >> 1) * 64 + l15;
#pragma unroll
    for (int j = 0; j < 4; ++j) {
        int lcol = lcol_b + j * 16;
        float bv = RELU ? bias[col0 + lcol] : 0.f;
#pragma unroll
        for (int i = 0; i < 4; ++i) {
#pragma unroll
            for (int r = 0; r < 4; ++r) {
                int lrow = lrow_b + i * 16 + r;
                float v = acc[i][j][r];
                if (RELU) v = fmaxf(v + bv, 0.f);
                if (SCALED) {
                    int dr = row0 + lrow; if (dr >= M) dr = M - 1;
                    v *= dinv[dr];
                }
                T[lrow * TP + lcol] = f2bf(v);
            }
        }
    }
    __syncthreads();
#pragma unroll
    for (int it = 0; it < 8; ++it) {
        int chunk = it * 256 + tid;          // 2048 chunks of 8 shorts
        int lr = chunk >> 4;
        int lc = (chunk & 15) * 8;
        int grow = row0 + lr;
        if (grow < M)
            *(bf16x8*)(Cb + (size_t)grow * N + col0 + lc) = *(const bf16x8*)&T[lr * TP + lc];
    }
}

// ---------------- bf16 gather aggregation, half-dim planes ----------------
// Global wave w in [0, 2N): half = w>=N (plane of 64 dims), wid = node.
// r = dd * ( Σ_{s in row d} hb[s][half] + hb[d][half] );  1 ushort per lane
// per gather = 128 B = one L2 line per edge. Dispatch-order monotonicity puts
// all plane-0 waves first -> concurrent working set 6.4 MB (fits per-XCD L2).

template <bool BR>
__launch_bounds__(256)
__global__ void agg_gather_kernel(const ushort* __restrict__ hb, const float* __restrict__ dinv,
                                  const int* __restrict__ rowptr, const ushort* __restrict__ csr,
                                  const float* __restrict__ bias,
                                  ushort* __restrict__ oh, int N) {
    int w = blockIdx.x * 4 + (threadIdx.x >> 6);   // global wave id, 0..2N-1
    int lane = threadIdx.x & 63;
    if (w >= 2 * N) return;
    int half = (w >= N) ? 1 : 0;
    int wid = w - half * N;
    int lo = rowptr[wid], hi = rowptr[wid + 1];
    float dd = dinv[wid];

    const ushort* hptr = hb + half * 64 + lane;    // element (2B) granularity

    float a0 = bf2f((short)hptr[(size_t)wid << 7]);   // self term
    float a1 = 0.f, a2 = 0.f, a3 = 0.f, a4 = 0.f, a5 = 0.f, a6 = 0.f, a7 = 0.f;

    for (int base = lo; base < hi; base += 64) {
        int cnt = min(64, hi - base);
        int sidx = (int)csr[base + (lane < cnt ? lane : cnt - 1)];   // coalesced chunk load
        int j = 0;
        for (; j + 8 <= cnt; j += 8) {
            int s0 = __shfl(sidx, j + 0, 64);
            int s1 = __shfl(sidx, j + 1, 64);
            int s2 = __shfl(sidx, j + 2, 64);
            int s3 = __shfl(sidx, j + 3, 64);
            int s4 = __shfl(sidx, j + 4, 64);
            int s5 = __shfl(sidx, j + 5, 64);
            int s6 = __shfl(sidx, j + 6, 64);
            int s7 = __shfl(sidx, j + 7, 64);
            ushort p0 = hptr[(size_t)s0 << 7];
            ushort p1 = hptr[(size_t)s1 << 7];
            ushort p2 = hptr[(size_t)s2 << 7];
            ushort p3 = hptr[(size_t)s3 << 7];
            ushort p4 = hptr[(size_t)s4 << 7];
            ushort p5 = hptr[(size_t)s5 << 7];
            ushort p6 = hptr[(size_t)s6 << 7];
            ushort p7 = hptr[(size_t)s7 << 7];
            a0 += bf2f((short)p0); a1 += bf2f((short)p1);
            a2 += bf2f((short)p2); a3 += bf2f((short)p3);
            a4 += bf2f((short)p4); a5 += bf2f((short)p5);
            a6 += bf2f((short)p6); a7 += bf2f((short)p7);
        }
        for (; j + 4 <= cnt; j += 4) {
            int s0 = __shfl(sidx, j + 0, 64);
            int s1 = __shfl(sidx, j + 1, 64);
            int s2 = __shfl(sidx, j + 2, 64);
            int s3 = __shfl(sidx, j + 3, 64);
            ushort p0 = hptr[(size_t)s0 << 7];
            ushort p1 = hptr[(size_t)s1 << 7];
            ushort p2 = hptr[(size_t)s2 << 7];
            ushort p3 = hptr[(size_t)s3 << 7];
            a0 += bf2f((short)p0); a1 += bf2f((short)p1);
            a2 += bf2f((short)p2); a3 += bf2f((short)p3);
        }
        for (; j < cnt; ++j) {
            int s = __shfl(sidx, j, 64);
            a0 += bf2f((short)hptr[(size_t)s << 7]);
        }
    }

    float r = dd * (((a0 + a1) + (a2 + a3)) + ((a4 + a5) + (a6 + a7)));
    if (BR) {
        r = fmaxf(r + bias[half * 64 + lane], 0.f);
    }
    oh[((size_t)wid << 7) + half * 64 + lane] = (ushort)f2bf(r);
}

// ---------------- pool (bf16 input) + fc ----------------

__launch_bounds__(128)
__global__ void pool_kernel(const ushort* __restrict__ h, const int* __restrict__ batch,
                            float* __restrict__ pool, int N) {
    int c = threadIdx.x;              // dim 0..127
    int i0 = blockIdx.x * PCH;
    if (i0 >= N) return;
    int i1 = min(i0 + PCH, N);
    int g = batch[i0];
    float acc = 0.f;
#pragma unroll 4
    for (int i = i0; i < i1; ++i) {
        int gi = batch[i];
        if (gi != g) {                // wave-uniform branch
            atomicAdd(&pool[g * HID2 + c], acc);
            acc = 0.f; g = gi;
        }
        acc += bf2f((short)h[(size_t)i * HID2 + c]);
    }
    atomicAdd(&pool[g * HID2 + c], acc);
}

__device__ __forceinline__ int lower_bound_i(const int* __restrict__ a, int n, int key) {
    int lo = 0, hi = n;
    while (lo < hi) {
        int mid = (lo + hi) >> 1;
        if (a[mid] < key) lo = mid + 1; else hi = mid;
    }
    return lo;
}

__global__ void fc_kernel(const float* __restrict__ pool, const int* __restrict__ batch,
                          const float* __restrict__ Wfc, const float* __restrict__ bfc,
                          float* __restrict__ out, int N) {
    int t = threadIdx.x;  // 256 = 64 graphs * 4 outputs
    int g = t >> 2, o = t & 3;
    int lo = lower_bound_i(batch, N, g);
    int hi = lower_bound_i(batch, N, g + 1);
    float acc = 0.f;
#pragma unroll 8
    for (int c = 0; c < HID2; ++c)
        acc = fmaf(pool[g * HID2 + c], Wfc[c * OUT_DIM + o], acc);
    float inv = 1.0f / fmaxf((float)(hi - lo), 1.0f);
    out[g * OUT_DIM + o] = acc * inv + bfc[o];
}

extern "C" void kernel_launch(void* const* d_in, const int* in_sizes, int n_in,
                              void* d_out, int out_size, void* d_ws, size_t ws_size,
                              hipStream_t stream) {
    const float* x   = (const float*)d_in[0];
    const int* src   = (const int*)d_in[1];
    const int* dst   = (const int*)d_in[2];
    const int* batch = (const int*)d_in[3];
    const float* W1  = (const float*)d_in[4];
    const float* b1  = (const float*)d_in[5];
    const float* W2  = (const float*)d_in[6];
    const float* b2  = (const float*)d_in[7];
    const float* Wfc = (const float*)d_in[8];
    const float* bfc = (const float*)d_in[9];
    float* out = (float*)d_out;

    const int N = in_sizes[0] / IN_DIM;  // 50000
    const int E = in_sizes[1];           // 640000
    const int NB = (N + 255) / 256;      // scan blocks (196)

    // ---- workspace layout (~50 MB; region aliasing) ----
    char* ws = (char*)d_ws;
    size_t off = 0;
    auto alloc = [&](size_t bytes) {
        char* p = ws + off;
        off = (off + bytes + 255) & ~(size_t)255;
        return p;
    };
    float*  dinv   = (float*) alloc((size_t)N * 4);
    int*    count  = (int*)   alloc((size_t)N * 4);
    int*    rowptr = (int*)   alloc((size_t)(N + 1) * 4);
    int*    bsums  = (int*)   alloc(256 * 4);
    ushort* rank   = (ushort*)alloc((size_t)E * 2);
    ushort* csr    = (ushort*)alloc((size_t)E * 2);
    short*  W1th   = (short*) alloc((size_t)IN_DIM * HID * 2);
    short*  W1tl   = (short*) alloc((size_t)IN_DIM * HID * 2);
    short*  W2th   = (short*) alloc((size_t)HID * HID2 * 2);
    short*  W2tl   = (short*) alloc((size_t)HID * HID2 * 2);
    // region Z (12.8 MB): xb -> later h2b (bf16)
    ushort* xb     = (ushort*)alloc((size_t)N * IN_DIM * 2);
    // region X (12.8 MB): axb (bf16) -> later a2b (bf16)
    short*  axb    = (short*) alloc((size_t)N * IN_DIM * 2);
    // a1 hi-only (25.6 MB)
    short*  a1h    = (short*) alloc((size_t)N * HID * 2);
    float*  pool   = (float*) alloc((size_t)NGRAPH * HID2 * 4);
    ushort* h2b = xb;              // xb dead after agg1
    short*  a2b = axb;             // ax dead after gemm1

    // ---- weight prep + count zero (one kernel, independent of graph) ----
    wprep_all_kernel<<<(max(IN_DIM * HID, N) + 255) / 256, 256, 0, stream>>>(
        W1, W1th, W1tl, W2, W2th, W2tl, count, N);

    // ---- CSR build (once; serves both layers) ----
    hist_kernel<<<(E + 255) / 256, 256, 0, stream>>>(dst, count, rank, E);
    scan1_kernel<<<NB, 256, 0, stream>>>(count, bsums, N);
    scan2_kernel<<<1, 256, 0, stream>>>(bsums, NB, pool);     // + pool zero
    scan3_kernel<<<NB, 256, 0, stream>>>(count, bsums, rowptr, dinv, N, E);
    scatter_scale_kernel<<<(N * 64 + 255) / 256, 256, 0, stream>>>(
        src, dst, rank, rowptr, csr, x, dinv, xb, E, N * 64);

    // ---- layer 1 ----
    agg_gather_kernel<false><<<(2 * N + 3) / 4, 256, 0, stream>>>(
        xb, dinv, rowptr, csr, nullptr, (ushort*)axb, N);
    gemm_tile_kernel<IN_DIM, HID, false, true, false>
        <<<dim3(HID / 128, (N + 127) / 128), 256, 0, stream>>>(
        axb, nullptr, W1th, W1tl, b1, nullptr, a1h, N);

    // ---- layer 2 ----
    gemm_tile_kernel<HID, HID2, false, false, true>
        <<<dim3(HID2 / 128, (N + 127) / 128), 256, 0, stream>>>(
        a1h, nullptr, W2th, W2tl, nullptr, dinv, (short*)h2b, N);
    agg_gather_kernel<true><<<(2 * N + 3) / 4, 256, 0, stream>>>(
        h2b, dinv, rowptr, csr, b2, (ushort*)a2b, N);

    // ---- pool + fc ----
    pool_kernel<<<(N + PCH - 1) / PCH, HID2, 0, stream>>>((const ushort*)a2b, batch, pool, N);
    fc_kernel<<<1, NGRAPH * OUT_DIM, 0, stream>>>(pool, batch, Wfc, bfc, out, N);
}

// Round 15
// 258.965 us; speedup vs baseline: 1.1027x; 1.1027x over previous
//
#include <hip/hip_runtime.h>

// GCN forward. All inter-kernel feature traffic in bf16.
//   xb  = bf16(x * dinv_row)                       (fused into scatter)
//   axb = bf16(dd*(Σ_{s} xb[s] + xb[d]))           (agg1, bf16 out)
//   a1  = relu(axb@W1 + b1)                        (MFMA GEMM, bf16 out)
//   h2b = bf16((a1@W2) * dinv_row)                 (MFMA GEMM, bf16 out)
//   a2b = bf16(relu(dd*(Σ h2b[s] + h2b[d]) + b2))  (agg2, bf16 out)
//   out = meanpool(a2b)@Wfc + bfc
// R15: REVERT r14's half-plane agg (regressed 262->286us: both planes co-resident
// so the working set never shrank while per-edge overhead doubled). This is the
// r13 configuration: full-row agg (4B/lane), atomic-free ushort CSR, 12 dispatches.

constexpr int IN_DIM  = 128;
constexpr int HID     = 256;
constexpr int HID2    = 128;
constexpr int OUT_DIM = 4;
constexpr int NGRAPH  = 64;
constexpr int PCH     = 64;   // nodes per pool block
constexpr int TP      = 132;  // epilogue LDS tile pitch (shorts)

typedef __attribute__((ext_vector_type(8))) short bf16x8;
typedef __attribute__((ext_vector_type(4))) float f32x4;

__device__ __forceinline__ short f2bf(float f) {
    union { float f; unsigned u; } v; v.f = f;
    unsigned r = v.u + 0x7fff + ((v.u >> 16) & 1);   // RNE
    return (short)(r >> 16);
}
__device__ __forceinline__ float bf2f(short s) {
    union { unsigned u; float f; } v; v.u = ((unsigned)(unsigned short)s) << 16;
    return v.f;
}

// ---------------- W prep (both layers) + count zero ----------------

__global__ void wprep_all_kernel(const float* __restrict__ W1, short* __restrict__ W1th,
                                 short* __restrict__ W1tl,
                                 const float* __restrict__ W2, short* __restrict__ W2th,
                                 short* __restrict__ W2tl,
                                 int* __restrict__ count, int N) {
    int i = blockIdx.x * blockDim.x + threadIdx.x;
    if (i < IN_DIM * HID) {
        int k = i / HID, n = i % HID;
        float w = W1[i];
        short h = f2bf(w);
        W1th[n * IN_DIM + k] = h;
        W1tl[n * IN_DIM + k] = f2bf(w - bf2f(h));
    }
    if (i < HID * HID2) {
        int k = i / HID2, n = i % HID2;
        float w = W2[i];
        short h = f2bf(w);
        W2th[n * HID + k] = h;
        W2tl[n * HID + k] = f2bf(w - bf2f(h));
    }
    if (i < N) count[i] = 0;
}

// ---------------- CSR build ----------------
// hist: count in-degree AND record each edge's rank within its dst row.

__global__ void hist_kernel(const int* __restrict__ dst, int* __restrict__ count,
                            ushort* __restrict__ rank, int E) {
    int i = blockIdx.x * blockDim.x + threadIdx.x;
    if (i < E) rank[i] = (ushort)atomicAdd(&count[dst[i]], 1);
}

__global__ void scan1_kernel(const int* __restrict__ count, int* __restrict__ bsums, int N) {
    __shared__ int s[256];
    int t = threadIdx.x, i = blockIdx.x * 256 + t;
    int v = (i < N) ? count[i] : 0;
    s[t] = v; __syncthreads();
    for (int o = 1; o < 256; o <<= 1) {
        int x = (t >= o) ? s[t - o] : 0;
        __syncthreads(); s[t] += x; __syncthreads();
    }
    if (t == 255) bsums[blockIdx.x] = s[255];
}

// exclusive scan of block sums (nb <= 256) + pool zeroing (piggyback)
__global__ void scan2_kernel(int* __restrict__ bsums, int nb, float* __restrict__ pool) {
    __shared__ int s[256];
    int t = threadIdx.x;
    int v = (t < nb) ? bsums[t] : 0;
    s[t] = v; __syncthreads();
    for (int o = 1; o < 256; o <<= 1) {
        int x = (t >= o) ? s[t - o] : 0;
        __syncthreads(); s[t] += x; __syncthreads();
    }
    if (t < nb) bsums[t] = s[t] - v;
    for (int i = t; i < NGRAPH * HID2; i += 256) pool[i] = 0.f;
}

__global__ void scan3_kernel(const int* __restrict__ count, const int* __restrict__ bsums,
                             int* __restrict__ rowptr, float* __restrict__ dinv, int N, int E) {
    __shared__ int s[256];
    int t = threadIdx.x, i = blockIdx.x * 256 + t;
    int v = (i < N) ? count[i] : 0;
    s[t] = v; __syncthreads();
    for (int o = 1; o < 256; o <<= 1) {
        int x = (t >= o) ? s[t - o] : 0;
        __syncthreads(); s[t] += x; __syncthreads();
    }
    if (i < N) {
        int ex = bsums[blockIdx.x] + s[t] - v;
        rowptr[i] = ex;
        dinv[i] = rsqrtf((float)v + 1.0f);
        if (i == 0) rowptr[N] = E;
    }
}

// scatter (no atomics: p = rowptr[dst]+rank) + xb = bf16(x * dinv_row)
__global__ void scatter_scale_kernel(const int* __restrict__ src, const int* __restrict__ dst,
                                     const ushort* __restrict__ rank,
                                     const int* __restrict__ rowptr, ushort* __restrict__ csr,
                                     const float* __restrict__ x, const float* __restrict__ dinv,
                                     ushort* __restrict__ xb, int E, int total2) {
    int i = blockIdx.x * blockDim.x + threadIdx.x;
    if (i < E) {
        int p = rowptr[dst[i]] + (int)rank[i];
        csr[p] = (ushort)src[i];
    }
    if (i < total2) {
        float d = dinv[i >> 6];
        float2 v = ((const float2*)x)[i];
        ushort2 o;
        o.x = (ushort)f2bf(v.x * d);
        o.y = (ushort)f2bf(v.y * d);
        ((ushort2*)xb)[i] = o;
    }
}

// ---------------- split-bf16 LDS-tiled MFMA GEMM, bf16 output ----------------
// Cb[M,N] = post( (Ah[+Al]) @ (Bh+Bl)^T ), B given N x K (transposed).
// Block: 128x128 tile, 256 thr. ALO: A has a lo plane (3 MFMAs) else 2 MFMAs.
// LDS slab = 16x32 tile in MFMA fragment order; single ds_read_b128 per frag.
// C/D layout (16x16x32): col=lane&15, row=(lane>>4)*4+reg [verified m89/m91].
// Epilogue: acc -> padded LDS bf16 tile (pitch TP=132) -> coalesced 16B stores.
// RELU: v=relu(v+bias[col]).  SCALED: v*=dinv[row] (pre-scale for gather table).

template <int K, int N, bool ALO, bool RELU, bool SCALED>
__launch_bounds__(256)
__global__ void gemm_tile_kernel(const short* __restrict__ Ah, const short* __restrict__ Al,
                                 const short* __restrict__ Bh, const short* __restrict__ Bl,
                                 const float* __restrict__ bias,
                                 const float* __restrict__ dinv,
                                 short* __restrict__ Cb, int M) {
    __shared__ __align__(16) short LDSBUF[128 * TP];     // 33792 B >= 32 KB staging
    short (*S)[8][512] = (short (*)[8][512])LDSBUF;      // staging view [4][8][512]

    const int tid  = threadIdx.x;
    const int wave = tid >> 6;
    const int lane = tid & 63;
    const int row0 = blockIdx.y * 128;
    const int col0 = blockIdx.x * 128;

    const int l15 = lane & 15;
    const int kq  = (lane >> 4) * 8;

    f32x4 acc[4][4];
#pragma unroll
    for (int i = 0; i < 4; ++i)
#pragma unroll
        for (int j = 0; j < 4; ++j) acc[i][j] = f32x4{0.f, 0.f, 0.f, 0.f};

    const int mt0 = (wave & 1) * 4;
    const int nt0 = (wave >> 1) * 4;

    for (int kb = 0; kb < K; kb += 32) {
        // ---- staging: constant-bound loops only ----
        if (ALO) {
            const short* gsrc = (wave == 0) ? Ah : (wave == 1) ? Al : (wave == 2) ? Bh : Bl;
            const bool isA = wave < 2;
            const int rb = (isA ? row0 : col0) + l15;
            bf16x8 stg[8];
#pragma unroll
            for (int j = 0; j < 8; ++j) {
                int rr = rb + j * 16;
                if (isA && rr >= M) rr = M - 1;       // clamp tail rows (stores guarded)
                stg[j] = *(const bf16x8*)(gsrc + (size_t)rr * K + kb + kq);
            }
#pragma unroll
            for (int j = 0; j < 8; ++j)
                *(bf16x8*)&S[wave][j][lane * 8] = stg[j];
        } else {
            if (wave < 2) {
                const int rb = row0 + l15;
                bf16x8 stg[4];
#pragma unroll
                for (int j = 0; j < 4; ++j) {
                    int rr = rb + (wave * 4 + j) * 16;
                    if (rr >= M) rr = M - 1;
                    stg[j] = *(const bf16x8*)(Ah + (size_t)rr * K + kb + kq);
                }
#pragma unroll
                for (int j = 0; j < 4; ++j)
                    *(bf16x8*)&S[0][wave * 4 + j][lane * 8] = stg[j];
            } else {
                const short* gsrc = (wave == 2) ? Bh : Bl;
                const int rb = col0 + l15;
                bf16x8 stg[8];
#pragma unroll
                for (int j = 0; j < 8; ++j)
                    stg[j] = *(const bf16x8*)(gsrc + (size_t)(rb + j * 16) * K + kb + kq);
#pragma unroll
                for (int j = 0; j < 8; ++j)
                    *(bf16x8*)&S[wave][j][lane * 8] = stg[j];
            }
        }
        __syncthreads();

        bf16x8 ah[4], al[4], bh[4], bl[4];
#pragma unroll
        for (int i = 0; i < 4; ++i) {
            ah[i] = *(const bf16x8*)&S[0][mt0 + i][lane * 8];
            if (ALO) al[i] = *(const bf16x8*)&S[1][mt0 + i][lane * 8];
            bh[i] = *(const bf16x8*)&S[2][nt0 + i][lane * 8];
            bl[i] = *(const bf16x8*)&S[3][nt0 + i][lane * 8];
        }
#pragma unroll
        for (int i = 0; i < 4; ++i)
#pragma unroll
            for (int j = 0; j < 4; ++j) {
                acc[i][j] = __builtin_amdgcn_mfma_f32_16x16x32_bf16(ah[i], bh[j], acc[i][j], 0, 0, 0);
                acc[i][j] = __builtin_amdgcn_mfma_f32_16x16x32_bf16(ah[i], bl[j], acc[i][j], 0, 0, 0);
                if (ALO)
                    acc[i][j] = __builtin_amdgcn_mfma_f32_16x16x32_bf16(al[i], bh[j], acc[i][j], 0, 0, 0);
            }
        __syncthreads();
    }

    // ---- epilogue: acc -> padded LDS bf16 tile -> coalesced stores ----
    short* T = LDSBUF;                      // 128 x TP shorts
    const int lrow_b = (wave & 1) * 64 + (lane >> 4) * 4;
    const int lcol_b = (wave >> 1) * 64 + l15;
#pragma unroll
    for (int j = 0; j < 4; ++j) {
        int lcol = lcol_b + j * 16;
        float bv = RELU ? bias[col0 + lcol] : 0.f;
#pragma unroll
        for (int i = 0; i < 4; ++i) {
#pragma unroll
            for (int r = 0; r < 4; ++r) {
                int lrow = lrow_b + i * 16 + r;
                float v = acc[i][j][r];
                if (RELU) v = fmaxf(v + bv, 0.f);
                if (SCALED) {
                    int dr = row0 + lrow; if (dr >= M) dr = M - 1;
                    v *= dinv[dr];
                }
                T[lrow * TP + lcol] = f2bf(v);
            }
        }
    }
    __syncthreads();
#pragma unroll
    for (int it = 0; it < 8; ++it) {
        int chunk = it * 256 + tid;          // 2048 chunks of 8 shorts
        int lr = chunk >> 4;
        int lc = (chunk & 15) * 8;
        int grow = row0 + lr;
        if (grow < M)
            *(bf16x8*)(Cb + (size_t)grow * N + col0 + lc) = *(const bf16x8*)&T[lr * TP + lc];
    }
}

// ---------------- bf16 gather aggregation (one wave per dst node, D=128) ----------------
// r = dd * ( Σ_{s in row d} hb[s] + hb[d] )   (hb pre-scaled by dinv[src])
// then [bias+relu]; output single-plane bf16. csr is ushort (N<65536).
// Inner loop unrolled x8 (≥4 outstanding gathers; L2-miss-path bound).

template <bool BR>
__launch_bounds__(256)
__global__ void agg_gather_kernel(const ushort* __restrict__ hb, const float* __restrict__ dinv,
                                  const int* __restrict__ rowptr, const ushort* __restrict__ csr,
                                  const float* __restrict__ bias,
                                  short* __restrict__ oh, int N) {
    int wid = (blockIdx.x * blockDim.x + threadIdx.x) >> 6;  // node id
    int lane = threadIdx.x & 63;
    if (wid >= N) return;
    int lo = rowptr[wid], hi = rowptr[wid + 1];
    float dd = dinv[wid];

    unsigned sv = *(const unsigned*)(hb + ((size_t)wid << 7) + (lane << 1));  // self term
    float a0x = bf2f((short)(sv & 0xffff)), a0y = bf2f((short)(sv >> 16));
    float a1x = 0.f, a1y = 0.f, a2x = 0.f, a2y = 0.f, a3x = 0.f, a3y = 0.f;
    float a4x = 0.f, a4y = 0.f, a5x = 0.f, a5y = 0.f, a6x = 0.f, a6y = 0.f;
    float a7x = 0.f, a7y = 0.f;

    const ushort* hptr = hb + (lane << 1);

    for (int base = lo; base < hi; base += 64) {
        int cnt = min(64, hi - base);
        int sidx = (int)csr[base + (lane < cnt ? lane : cnt - 1)];   // coalesced chunk load
        int j = 0;
        for (; j + 8 <= cnt; j += 8) {
            int s0 = __shfl(sidx, j + 0, 64);
            int s1 = __shfl(sidx, j + 1, 64);
            int s2 = __shfl(sidx, j + 2, 64);
            int s3 = __shfl(sidx, j + 3, 64);
            int s4 = __shfl(sidx, j + 4, 64);
            int s5 = __shfl(sidx, j + 5, 64);
            int s6 = __shfl(sidx, j + 6, 64);
            int s7 = __shfl(sidx, j + 7, 64);
            unsigned p0 = *(const unsigned*)(hptr + ((size_t)s0 << 7));
            unsigned p1 = *(const unsigned*)(hptr + ((size_t)s1 << 7));
            unsigned p2 = *(const unsigned*)(hptr + ((size_t)s2 << 7));
            unsigned p3 = *(const unsigned*)(hptr + ((size_t)s3 << 7));
            unsigned p4 = *(const unsigned*)(hptr + ((size_t)s4 << 7));
            unsigned p5 = *(const unsigned*)(hptr + ((size_t)s5 << 7));
            unsigned p6 = *(const unsigned*)(hptr + ((size_t)s6 << 7));
            unsigned p7 = *(const unsigned*)(hptr + ((size_t)s7 << 7));
            a0x += bf2f((short)(p0 & 0xffff)); a0y += bf2f((short)(p0 >> 16));
            a1x += bf2f((short)(p1 & 0xffff)); a1y += bf2f((short)(p1 >> 16));
            a2x += bf2f((short)(p2 & 0xffff)); a2y += bf2f((short)(p2 >> 16));
            a3x += bf2f((short)(p3 & 0xffff)); a3y += bf2f((short)(p3 >> 16));
            a4x += bf2f((short)(p4 & 0xffff)); a4y += bf2f((short)(p4 >> 16));
            a5x += bf2f((short)(p5 & 0xffff)); a5y += bf2f((short)(p5 >> 16));
            a6x += bf2f((short)(p6 & 0xffff)); a6y += bf2f((short)(p6 >> 16));
            a7x += bf2f((short)(p7 & 0xffff)); a7y += bf2f((short)(p7 >> 16));
        }
        for (; j + 4 <= cnt; j += 4) {
            int s0 = __shfl(sidx, j + 0, 64);
            int s1 = __shfl(sidx, j + 1, 64);
            int s2 = __shfl(sidx, j + 2, 64);
            int s3 = __shfl(sidx, j + 3, 64);
            unsigned p0 = *(const unsigned*)(hptr + ((size_t)s0 << 7));
            unsigned p1 = *(const unsigned*)(hptr + ((size_t)s1 << 7));
            unsigned p2 = *(const unsigned*)(hptr + ((size_t)s2 << 7));
            unsigned p3 = *(const unsigned*)(hptr + ((size_t)s3 << 7));
            a0x += bf2f((short)(p0 & 0xffff)); a0y += bf2f((short)(p0 >> 16));
            a1x += bf2f((short)(p1 & 0xffff)); a1y += bf2f((short)(p1 >> 16));
            a2x += bf2f((short)(p2 & 0xffff)); a2y += bf2f((short)(p2 >> 16));
            a3x += bf2f((short)(p3 & 0xffff)); a3y += bf2f((short)(p3 >> 16));
        }
        for (; j < cnt; ++j) {
            int s = __shfl(sidx, j, 64);
            unsigned pv = *(const unsigned*)(hptr + ((size_t)s << 7));
            a0x += bf2f((short)(pv & 0xffff)); a0y += bf2f((short)(pv >> 16));
        }
    }

    float rx = dd * (((a0x + a1x) + (a2x + a3x)) + ((a4x + a5x) + (a6x + a7x)));
    float ry = dd * (((a0y + a1y) + (a2y + a3y)) + ((a4y + a5y) + (a6y + a7y)));
    if (BR) {
        float2 b = ((const float2*)bias)[lane];
        rx = fmaxf(rx + b.x, 0.f);
        ry = fmaxf(ry + b.y, 0.f);
    }
    short2 hv; hv.x = f2bf(rx); hv.y = f2bf(ry);
    *(short2*)&oh[(size_t)wid * 128 + lane * 2] = hv;
}

// ---------------- pool (bf16 input) + fc ----------------

__launch_bounds__(128)
__global__ void pool_kernel(const ushort* __restrict__ h, const int* __restrict__ batch,
                            float* __restrict__ pool, int N) {
    int c = threadIdx.x;              // dim 0..127
    int i0 = blockIdx.x * PCH;
    if (i0 >= N) return;
    int i1 = min(i0 + PCH, N);
    int g = batch[i0];
    float acc = 0.f;
#pragma unroll 4
    for (int i = i0; i < i1; ++i) {
        int gi = batch[i];
        if (gi != g) {                // wave-uniform branch
            atomicAdd(&pool[g * HID2 + c], acc);
            acc = 0.f; g = gi;
        }
        acc += bf2f((short)h[(size_t)i * HID2 + c]);
    }
    atomicAdd(&pool[g * HID2 + c], acc);
}

__device__ __forceinline__ int lower_bound_i(const int* __restrict__ a, int n, int key) {
    int lo = 0, hi = n;
    while (lo < hi) {
        int mid = (lo + hi) >> 1;
        if (a[mid] < key) lo = mid + 1; else hi = mid;
    }
    return lo;
}

__global__ void fc_kernel(const float* __restrict__ pool, const int* __restrict__ batch,
                          const float* __restrict__ Wfc, const float* __restrict__ bfc,
                          float* __restrict__ out, int N) {
    int t = threadIdx.x;  // 256 = 64 graphs * 4 outputs
    int g = t >> 2, o = t & 3;
    int lo = lower_bound_i(batch, N, g);
    int hi = lower_bound_i(batch, N, g + 1);
    float acc = 0.f;
#pragma unroll 8
    for (int c = 0; c < HID2; ++c)
        acc = fmaf(pool[g * HID2 + c], Wfc[c * OUT_DIM + o], acc);
    float inv = 1.0f / fmaxf((float)(hi - lo), 1.0f);
    out[g * OUT_DIM + o] = acc * inv + bfc[o];
}

extern "C" void kernel_launch(void* const* d_in, const int* in_sizes, int n_in,
                              void* d_out, int out_size, void* d_ws, size_t ws_size,
                              hipStream_t stream) {
    const float* x   = (const float*)d_in[0];
    const int* src   = (const int*)d_in[1];
    const int* dst   = (const int*)d_in[2];
    const int* batch = (const int*)d_in[3];
    const float* W1  = (const float*)d_in[4];
    const float* b1  = (const float*)d_in[5];
    const float* W2  = (const float*)d_in[6];
    const float* b2  = (const float*)d_in[7];
    const float* Wfc = (const float*)d_in[8];
    const float* bfc = (const float*)d_in[9];
    float* out = (float*)d_out;

    const int N = in_sizes[0] / IN_DIM;  // 50000
    const int E = in_sizes[1];           // 640000
    const int NB = (N + 255) / 256;      // scan blocks (196)

    // ---- workspace layout (~50 MB; region aliasing) ----
    char* ws = (char*)d_ws;
    size_t off = 0;
    auto alloc = [&](size_t bytes) {
        char* p = ws + off;
        off = (off + bytes + 255) & ~(size_t)255;
        return p;
    };
    float*  dinv   = (float*) alloc((size_t)N * 4);
    int*    count  = (int*)   alloc((size_t)N * 4);
    int*    rowptr = (int*)   alloc((size_t)(N + 1) * 4);
    int*    bsums  = (int*)   alloc(256 * 4);
    ushort* rank   = (ushort*)alloc((size_t)E * 2);
    ushort* csr    = (ushort*)alloc((size_t)E * 2);
    short*  W1th   = (short*) alloc((size_t)IN_DIM * HID * 2);
    short*  W1tl   = (short*) alloc((size_t)IN_DIM * HID * 2);
    short*  W2th   = (short*) alloc((size_t)HID * HID2 * 2);
    short*  W2tl   = (short*) alloc((size_t)HID * HID2 * 2);
    // region Z (12.8 MB): xb -> later h2b (bf16)
    ushort* xb     = (ushort*)alloc((size_t)N * IN_DIM * 2);
    // region X (12.8 MB): axb (bf16) -> later a2b (bf16)
    short*  axb    = (short*) alloc((size_t)N * IN_DIM * 2);
    // a1 hi-only (25.6 MB)
    short*  a1h    = (short*) alloc((size_t)N * HID * 2);
    float*  pool   = (float*) alloc((size_t)NGRAPH * HID2 * 4);
    ushort* h2b = xb;              // xb dead after agg1
    short*  a2b = axb;             // ax dead after gemm1

    // ---- weight prep + count zero (one kernel, independent of graph) ----
    wprep_all_kernel<<<(max(IN_DIM * HID, N) + 255) / 256, 256, 0, stream>>>(
        W1, W1th, W1tl, W2, W2th, W2tl, count, N);

    // ---- CSR build (once; serves both layers) ----
    hist_kernel<<<(E + 255) / 256, 256, 0, stream>>>(dst, count, rank, E);
    scan1_kernel<<<NB, 256, 0, stream>>>(count, bsums, N);
    scan2_kernel<<<1, 256, 0, stream>>>(bsums, NB, pool);     // + pool zero
    scan3_kernel<<<NB, 256, 0, stream>>>(count, bsums, rowptr, dinv, N, E);
    scatter_scale_kernel<<<(N * 64 + 255) / 256, 256, 0, stream>>>(
        src, dst, rank, rowptr, csr, x, dinv, xb, E, N * 64);

    // ---- layer 1 ----
    agg_gather_kernel<false><<<(N + 3) / 4, 256, 0, stream>>>(
        xb, dinv, rowptr, csr, nullptr, axb, N);
    gemm_tile_kernel<IN_DIM, HID, false, true, false>
        <<<dim3(HID / 128, (N + 127) / 128), 256, 0, stream>>>(
        axb, nullptr, W1th, W1tl, b1, nullptr, a1h, N);

    // ---- layer 2 ----
    gemm_tile_kernel<HID, HID2, false, false, true>
        <<<dim3(HID2 / 128, (N + 127) / 128), 256, 0, stream>>>(
        a1h, nullptr, W2th, W2tl, nullptr, dinv, (short*)h2b, N);
    agg_gather_kernel<true><<<(N + 3) / 4, 256, 0, stream>>>(
        h2b, dinv, rowptr, csr, b2, a2b, N);

    // ---- pool + fc ----
    pool_kernel<<<(N + PCH - 1) / PCH, HID2, 0, stream>>>((const ushort*)a2b, batch, pool, N);
    fc_kernel<<<1, NGRAPH * OUT_DIM, 0, stream>>>(pool, batch, Wfc, bfc, out, N);
}